// Round 3
// baseline (679.639 us; speedup 1.0000x reference)
//
#include <hip/hip_runtime.h>

// Problem constants (match reference shapes)
#define B_ 2
#define N_ 8192
#define T_ 32
#define C_ 64
#define K_ 16
#define NB_ 4

#define NC 16   // nodes per block
#define TC 2    // t-rows per phase (per batch)
// block = 128 threads: lane = tid&15 covers C=64 via float4; np = tid>>4 (0..7)
// owns the node pair {2np, 2np+1}. Each thread: 2 nodes x 2 rows x 16 k
// = 64 float4 gather loads in flight (R1-level MLP, phase-local like R2).
// grid: x = N/NC = 512 node-chunks, y = B*T/TC = 32 phases (x-fastest dispatch
// keeps the active 4 MiB z-slice L2/L3-resident).

typedef float f4v __attribute__((ext_vector_type(4)));

__device__ __forceinline__ float tanh_fast(float x) {
    return 1.f - 2.f / (__expf(2.f * x) + 1.f);
}

__device__ __forceinline__ f4v tanh4(f4v a) {
    f4v r;
    r.x = tanh_fast(a.x); r.y = tanh_fast(a.y);
    r.z = tanh_fast(a.z); r.w = tanh_fast(a.w);
    return r;
}

__global__ __launch_bounds__(128, 5) void geodcd_kernel(
    const float* __restrict__ z,      // (B, N, T, C)
    const int*   __restrict__ nidx,   // (N, K)
    const float* __restrict__ adj,    // (N, K)
    const float* __restrict__ bw,     // (NB, N, K)
    const float* __restrict__ cc,     // (C, NB)
    float*       __restrict__ out)    // (B, N, T, C)
{
    const int tid = threadIdx.x;
    const int n0  = blockIdx.x * NC;
    const int ph  = blockIdx.y;            // 0..31
    const int b   = ph >> 4;               // batch
    const int t0  = (ph & 15) * TC;        // first t-row of this phase

    // [k][node] layouts: within a wave, 8 node-values x 16B stride hit 8
    // distinct banks (conflict-free); idx pairs are adjacent -> ds_read_b64.
    __shared__ int idx2[K_][NC];                       // 1 KiB
    __shared__ __align__(16) float qk[K_][NC][NB_];    // adj*bw, 4 KiB

    for (int i = tid; i < K_ * NC; i += 128) {
        const int k = i >> 4, nl = i & 15;
        idx2[k][nl] = nidx[(n0 + nl) * K_ + k];
    }
    for (int i = tid; i < K_ * NC * NB_; i += 128) {
        const int k = i >> 6, nl = (i >> 2) & 15, bb = i & 3;
        qk[k][nl][bb] = adj[(n0 + nl) * K_ + k] * bw[(bb * N_ + (n0 + nl)) * K_ + k];
    }
    __syncthreads();

    const int lane = tid & 15;
    const int np   = tid >> 4;       // 0..7
    const int c4   = lane * 4;
    const int nlo  = 2 * np;         // local node pair {nlo, nlo+1}

    // cc fragment in registers: ccv[j][b] = cc[c4+j][b]  (16 VGPR)
    f4v ccv[4];
#pragma unroll
    for (int j = 0; j < 4; ++j)
        ccv[j] = *(const f4v*)&cc[(c4 + j) * NB_];

    const float* zb = z + (size_t)b * (N_ * T_ * C_);
    const int rowbase = t0 * C_ + c4;

    f4v a00 = {0.f,0.f,0.f,0.f}, a01 = {0.f,0.f,0.f,0.f};  // node0, rows t0/t0+1
    f4v a10 = {0.f,0.f,0.f,0.f}, a11 = {0.f,0.f,0.f,0.f};  // node1

#pragma unroll
    for (int k = 0; k < K_; ++k) {
        const int j0 = idx2[k][nlo];
        const int j1 = idx2[k][nlo + 1];
        const f4v q0 = *(const f4v*)qk[k][nlo];
        const f4v q1 = *(const f4v*)qk[k][nlo + 1];

        // Recompute 4-wide edge weights from registers (no w[16] array)
        f4v w0, w1;
        w0.x = ccv[0].x*q0.x + ccv[0].y*q0.y + ccv[0].z*q0.z + ccv[0].w*q0.w;
        w0.y = ccv[1].x*q0.x + ccv[1].y*q0.y + ccv[1].z*q0.z + ccv[1].w*q0.w;
        w0.z = ccv[2].x*q0.x + ccv[2].y*q0.y + ccv[2].z*q0.z + ccv[2].w*q0.w;
        w0.w = ccv[3].x*q0.x + ccv[3].y*q0.y + ccv[3].z*q0.z + ccv[3].w*q0.w;
        w1.x = ccv[0].x*q1.x + ccv[0].y*q1.y + ccv[0].z*q1.z + ccv[0].w*q1.w;
        w1.y = ccv[1].x*q1.x + ccv[1].y*q1.y + ccv[1].z*q1.z + ccv[1].w*q1.w;
        w1.z = ccv[2].x*q1.x + ccv[2].y*q1.y + ccv[2].z*q1.z + ccv[2].w*q1.w;
        w1.w = ccv[3].x*q1.x + ccv[3].y*q1.y + ccv[3].z*q1.z + ccv[3].w*q1.w;

        const float* p0 = zb + j0 * (T_ * C_) + rowbase;
        const float* p1 = zb + j1 * (T_ * C_) + rowbase;
        const f4v v00 = *(const f4v*)p0;
        const f4v v01 = *(const f4v*)(p0 + C_);
        const f4v v10 = *(const f4v*)p1;
        const f4v v11 = *(const f4v*)(p1 + C_);

        a00.x += v00.x*w0.x; a00.y += v00.y*w0.y; a00.z += v00.z*w0.z; a00.w += v00.w*w0.w;
        a01.x += v01.x*w0.x; a01.y += v01.y*w0.y; a01.z += v01.z*w0.z; a01.w += v01.w*w0.w;
        a10.x += v10.x*w1.x; a10.y += v10.y*w1.y; a10.z += v10.z*w1.z; a10.w += v10.w*w1.w;
        a11.x += v11.x*w1.x; a11.y += v11.y*w1.y; a11.z += v11.z*w1.z; a11.w += v11.w*w1.w;
    }

    // Nontemporal stores: keep the hot z slice in L2/L3
    float* o0 = out + (((size_t)b * N_ + (n0 + nlo)) * T_ + t0) * C_ + c4;
    float* o1 = out + (((size_t)b * N_ + (n0 + nlo + 1)) * T_ + t0) * C_ + c4;
    __builtin_nontemporal_store(tanh4(a00), (f4v*)o0);
    __builtin_nontemporal_store(tanh4(a01), (f4v*)(o0 + C_));
    __builtin_nontemporal_store(tanh4(a10), (f4v*)o1);
    __builtin_nontemporal_store(tanh4(a11), (f4v*)(o1 + C_));
}

extern "C" void kernel_launch(void* const* d_in, const int* in_sizes, int n_in,
                              void* d_out, int out_size, void* d_ws, size_t ws_size,
                              hipStream_t stream) {
    const float* z    = (const float*)d_in[0];
    const int*   nidx = (const int*)  d_in[1];
    const float* adj  = (const float*)d_in[2];
    const float* bw   = (const float*)d_in[3];
    const float* cc   = (const float*)d_in[4];
    float*       out  = (float*)d_out;

    dim3 grid(N_ / NC, B_ * (T_ / TC));
    geodcd_kernel<<<grid, 128, 0, stream>>>(z, nidx, adj, bw, cc, out);
}